// Round 1
// baseline (716.335 us; speedup 1.0000x reference)
//
#include <hip/hip_runtime.h>
#include <hip/hip_bf16.h>

// TAGConv: K=2 hops, D_IN=128, D_OUT=128.
// h_{k+1}[v] = norm[v] * sum_{(u->v)} norm[u] * h_k[u];  norm = deg(dst)^-0.5
// out = [feat, h1, h2] @ W^T + b
//
// Strategy: build CSR (deg -> exclusive scan -> int-atomic scatter), then
// gather-based SpMM (one wave per dst node, float2 per lane), then tiled
// fp32 GEMM (no fp32 MFMA on CDNA4 -> vector ALU).

#define D 128
#define TPB 256

// ---------------- degree ----------------
__global__ void deg_kernel(const int* __restrict__ dst, int* __restrict__ deg, int e) {
    int i = blockIdx.x * TPB + threadIdx.x;
    if (i < e) atomicAdd(&deg[dst[i]], 1);
}

// ---------------- 3-phase exclusive scan over deg (N ~ 100k) ----------------
__global__ void scan1_kernel(const int* __restrict__ deg, int* __restrict__ rs,
                             int* __restrict__ bsum, int n) {
    __shared__ int s[TPB];
    int t = threadIdx.x;
    int i = blockIdx.x * TPB + t;
    int v = (i < n) ? deg[i] : 0;
    s[t] = v;
    __syncthreads();
    for (int off = 1; off < TPB; off <<= 1) {
        int x = (t >= off) ? s[t - off] : 0;
        __syncthreads();
        s[t] += x;
        __syncthreads();
    }
    if (i < n) rs[i] = s[t] - v;            // exclusive
    if (t == TPB - 1) bsum[blockIdx.x] = s[t];
}

__global__ void scan2_kernel(int* __restrict__ bsum, int nb) {
    __shared__ int s[512];
    int t = threadIdx.x;
    int v = (t < nb) ? bsum[t] : 0;
    s[t] = v;
    __syncthreads();
    for (int off = 1; off < 512; off <<= 1) {
        int x = (t >= off) ? s[t - off] : 0;
        __syncthreads();
        s[t] += x;
        __syncthreads();
    }
    if (t < nb) bsum[t] = s[t] - v;         // exclusive
}

// finalize row_start (+= block offset), rs[n] = E, and norm = rsqrt(deg)
__global__ void finalize_kernel(int* __restrict__ rs, const int* __restrict__ bsum,
                                const int* __restrict__ deg, float* __restrict__ norm,
                                int n, int e_total) {
    int i = blockIdx.x * TPB + threadIdx.x;
    if (i < n) {
        rs[i] += bsum[blockIdx.x];
        norm[i] = rsqrtf((float)deg[i]);    // deg >= 1 guaranteed by problem
    }
    if (i == n) rs[n] = e_total;
}

// ---------------- CSR scatter (order within row irrelevant: sum) ----------------
__global__ void scatter_kernel(const int* __restrict__ src, const int* __restrict__ dst,
                               const int* __restrict__ rs, int* __restrict__ cursor,
                               int* __restrict__ csr, int e) {
    int i = blockIdx.x * TPB + threadIdx.x;
    if (i < e) {
        int v = dst[i];
        int pos = rs[v] + atomicAdd(&cursor[v], 1);
        csr[pos] = src[i];
    }
}

// ---------------- gather SpMM: one wave per dst node ----------------
__global__ __launch_bounds__(TPB) void spmm_kernel(
    const float* __restrict__ hin, float* __restrict__ hout,
    const int* __restrict__ rs, const int* __restrict__ csr,
    const float* __restrict__ norm, int n) {
    int w = (blockIdx.x * TPB + threadIdx.x) >> 6;   // node
    int lane = threadIdx.x & 63;                     // 2 cols/lane
    if (w >= n) return;
    int beg = rs[w], end = rs[w + 1];
    float ax = 0.f, ay = 0.f;
    for (int i = beg; i < end; ++i) {
        int u = csr[i];
        float s = norm[u];
        float2 hv = ((const float2*)(hin + (size_t)u * D))[lane];
        ax += s * hv.x;
        ay += s * hv.y;
    }
    float nv = norm[w];
    float2 r;
    r.x = ax * nv;
    r.y = ay * nv;
    ((float2*)(hout + (size_t)w * D))[lane] = r;
}

// ---------------- GEMM: out[n][128] = [feat|h1|h2][n][384] @ W^T + b ----------------
#define BM 64
#define BK 32
__global__ __launch_bounds__(TPB) void gemm_kernel(
    const float* __restrict__ feat, const float* __restrict__ h1,
    const float* __restrict__ h2, const float* __restrict__ W,
    const float* __restrict__ bias, float* __restrict__ out, int n) {
    __shared__ float Xs[BM][BK + 4];   // stride 36 floats (16B-aligned rows)
    __shared__ float Wt[BK][132];      // transposed W tile, padded stride

    int tid = threadIdx.x;
    int block_m = blockIdx.x * BM;
    int og = (tid & 31) * 4;           // output col base (float4)
    int mg = (tid >> 5) * 8;           // node base within tile

    float acc[8][4] = {};

    for (int kc = 0; kc < 12; ++kc) {
        const float* srcp = (kc < 4) ? feat : (kc < 8 ? h1 : h2);
        int c0 = (kc & 3) * 32;

        // X tile: 64 rows x 32 cols, 2 float4 per thread
        {
            int r = tid >> 3;
            int c4 = (tid & 7) * 4;
#pragma unroll
            for (int half = 0; half < 2; ++half) {
                int rr = r + half * 32;
                int node = block_m + rr;
                float4 v = make_float4(0.f, 0.f, 0.f, 0.f);
                if (node < n) v = *(const float4*)(srcp + (size_t)node * D + c0 + c4);
                *(float4*)&Xs[rr][c4] = v;
            }
        }
        // W tile (transposed in LDS): 128 outs x 32 k, 4 float4 per thread
        {
#pragma unroll
            for (int it = 0; it < 4; ++it) {
                int idx = tid + TPB * it;     // 0..1023
                int o = idx >> 3;             // 0..127
                int d4 = (idx & 7) * 4;       // 0..28
                float4 wv = *(const float4*)(W + (size_t)o * 384 + kc * 32 + d4);
                Wt[d4 + 0][o] = wv.x;
                Wt[d4 + 1][o] = wv.y;
                Wt[d4 + 2][o] = wv.z;
                Wt[d4 + 3][o] = wv.w;
            }
        }
        __syncthreads();

#pragma unroll
        for (int k = 0; k < BK; ++k) {
            float4 wv = *(const float4*)&Wt[k][og];
#pragma unroll
            for (int i = 0; i < 8; ++i) {
                float x = Xs[mg + i][k];
                acc[i][0] += x * wv.x;
                acc[i][1] += x * wv.y;
                acc[i][2] += x * wv.z;
                acc[i][3] += x * wv.w;
            }
        }
        __syncthreads();
    }

    float4 bv = *(const float4*)(bias + og);
#pragma unroll
    for (int i = 0; i < 8; ++i) {
        int node = block_m + mg + i;
        if (node < n) {
            float4 r;
            r.x = acc[i][0] + bv.x;
            r.y = acc[i][1] + bv.y;
            r.z = acc[i][2] + bv.z;
            r.w = acc[i][3] + bv.w;
            *(float4*)(out + (size_t)node * D + og) = r;
        }
    }
}

extern "C" void kernel_launch(void* const* d_in, const int* in_sizes, int n_in,
                              void* d_out, int out_size, void* d_ws, size_t ws_size,
                              hipStream_t stream) {
    const float* feat = (const float*)d_in[0];
    const int* src    = (const int*)d_in[1];
    const int* dst    = (const int*)d_in[2];
    const float* W    = (const float*)d_in[3];
    const float* bias = (const float*)d_in[4];
    float* out        = (float*)d_out;

    const int N = in_sizes[0] / D;     // 100000
    const int E = in_sizes[1];         // 1600000

    // workspace layout (256B aligned bump allocator)
    char* ws = (char*)d_ws;
    size_t off = 0;
    auto bump = [&](size_t bytes) {
        char* p = ws + off;
        off += (bytes + 255) & ~(size_t)255;
        return p;
    };
    int* deg      = (int*)bump((size_t)N * 4);       // zeroed below (adjacent w/ cursor)
    int* cursor   = (int*)bump((size_t)N * 4);       // zeroed below
    float* norm   = (float*)bump((size_t)N * 4);
    int* rs       = (int*)bump((size_t)(N + 1) * 4);
    int* bsum     = (int*)bump(512 * 4);
    int* csr      = (int*)bump((size_t)E * 4);
    float* h1     = (float*)bump((size_t)N * D * 4);
    float* h2     = (float*)bump((size_t)N * D * 4);
    (void)ws_size;

    const int nb_n = (N + TPB - 1) / TPB;            // 391
    const int nb_e = (E + TPB - 1) / TPB;            // 6250
    const int nb_n1 = (N + 1 + TPB - 1) / TPB;       // covers i==N

    // zero deg + cursor in one shot (they are adjacent)
    hipMemsetAsync(deg, 0, ((size_t)N * 4 + 255 & ~(size_t)255) + (size_t)N * 4, stream);

    deg_kernel<<<nb_e, TPB, 0, stream>>>(dst, deg, E);
    scan1_kernel<<<nb_n, TPB, 0, stream>>>(deg, rs, bsum, N);
    scan2_kernel<<<1, 512, 0, stream>>>(bsum, nb_n);
    finalize_kernel<<<nb_n1, TPB, 0, stream>>>(rs, bsum, deg, norm, N, E);
    scatter_kernel<<<nb_e, TPB, 0, stream>>>(src, dst, rs, cursor, csr, E);

    const int spmm_blocks = (N * 64 + TPB - 1) / TPB;  // 1 wave per node
    spmm_kernel<<<spmm_blocks, TPB, 0, stream>>>(feat, h1, rs, csr, norm, N);
    spmm_kernel<<<spmm_blocks, TPB, 0, stream>>>(h1, h2, rs, csr, norm, N);

    const int gemm_blocks = (N + BM - 1) / BM;
    gemm_kernel<<<gemm_blocks, TPB, 0, stream>>>(feat, h1, h2, W, bias, out, N);
}

// Round 2
// 653.874 us; speedup vs baseline: 1.0955x; 1.0955x over previous
//
#include <hip/hip_runtime.h>
#include <hip/hip_bf16.h>

// TAGConv K=2, D=128. Round 2: bf16 gather rows (half traffic, norm pre-folded)
// + bf16 MFMA GEMM with fp32 accumulate.
//
// h1 = norm * (A @ (feat*norm));  h2 = norm * (A @ (h1*norm))
// out = [feat|h1|h2] @ W^T + b   (bf16 inputs, fp32 accum via mfma_f32_16x16x32_bf16)

#define D 128
#define TPB 256

typedef __attribute__((ext_vector_type(8))) short short8;
typedef __attribute__((ext_vector_type(4))) float f32x4;

__device__ __forceinline__ ushort f2bf(float f) {
    unsigned u = __float_as_uint(f);
    u += 0x7fff + ((u >> 16) & 1);      // round-to-nearest-even
    return (ushort)(u >> 16);
}
__device__ __forceinline__ unsigned pack2bf(float x, float y) {
    return (unsigned)f2bf(x) | ((unsigned)f2bf(y) << 16);
}

// ---------------- degree ----------------
__global__ void deg_kernel(const int* __restrict__ dst, int* __restrict__ deg, int e) {
    int i = blockIdx.x * TPB + threadIdx.x;
    if (i < e) atomicAdd(&deg[dst[i]], 1);
}

// ---------------- exclusive scan over deg ----------------
__global__ void scan1_kernel(const int* __restrict__ deg, int* __restrict__ rs,
                             int* __restrict__ bsum, int n) {
    __shared__ int s[TPB];
    int t = threadIdx.x;
    int i = blockIdx.x * TPB + t;
    int v = (i < n) ? deg[i] : 0;
    s[t] = v;
    __syncthreads();
    for (int off = 1; off < TPB; off <<= 1) {
        int x = (t >= off) ? s[t - off] : 0;
        __syncthreads();
        s[t] += x;
        __syncthreads();
    }
    if (i < n) rs[i] = s[t] - v;
    if (t == TPB - 1) bsum[blockIdx.x] = s[t];
}

__global__ void scan2_kernel(int* __restrict__ bsum, int nb) {
    __shared__ int s[512];
    int t = threadIdx.x;
    int v = (t < nb) ? bsum[t] : 0;
    s[t] = v;
    __syncthreads();
    for (int off = 1; off < 512; off <<= 1) {
        int x = (t >= off) ? s[t - off] : 0;
        __syncthreads();
        s[t] += x;
        __syncthreads();
    }
    if (t < nb) bsum[t] = s[t] - v;
}

__global__ void finalize_kernel(int* __restrict__ rs, const int* __restrict__ bsum,
                                const int* __restrict__ deg, float* __restrict__ norm,
                                int n, int e_total) {
    int i = blockIdx.x * TPB + threadIdx.x;
    if (i < n) {
        rs[i] += bsum[blockIdx.x];
        norm[i] = rsqrtf((float)deg[i]);
    }
    if (i == n) rs[n] = e_total;
}

// ---------------- CSR scatter ----------------
__global__ void scatter_kernel(const int* __restrict__ src, const int* __restrict__ dst,
                               const int* __restrict__ rs, int* __restrict__ cursor,
                               int* __restrict__ csr, int e) {
    int i = blockIdx.x * TPB + threadIdx.x;
    if (i < e) {
        int v = dst[i];
        int pos = rs[v] + atomicAdd(&cursor[v], 1);
        csr[pos] = src[i];
    }
}

// ---------------- prescale: featb = bf16(feat), h0s = bf16(feat*norm) ----------------
__global__ __launch_bounds__(TPB) void prescale_kernel(
    const float* __restrict__ feat, const float* __restrict__ norm,
    unsigned* __restrict__ featb, unsigned* __restrict__ h0s, int n) {
    int gid = blockIdx.x * TPB + threadIdx.x;
    int node = gid >> 6, c = gid & 63;
    if (node >= n) return;
    float2 f = ((const float2*)(feat + (size_t)node * D))[c];
    float nv = norm[node];
    featb[(size_t)node * 64 + c] = pack2bf(f.x, f.y);
    h0s[(size_t)node * 64 + c]   = pack2bf(f.x * nv, f.y * nv);
}

// ---------------- W -> bf16 ----------------
__global__ void wconv_kernel(const float* __restrict__ W, ushort* __restrict__ Wb, int n) {
    int i = blockIdx.x * TPB + threadIdx.x;
    if (i < n) Wb[i] = f2bf(W[i]);
}

// ---------------- SpMM hop 1: gather pre-scaled bf16 rows ----------------
// writes h1b = bf16(h1)   (h1 = norm[v] * sum)
__global__ __launch_bounds__(TPB) void spmm1_kernel(
    const unsigned* __restrict__ h0s, const int* __restrict__ rs,
    const int* __restrict__ csr, const float* __restrict__ norm,
    unsigned* __restrict__ h1b, int n) {
    int gid = blockIdx.x * TPB + threadIdx.x;
    int w = gid >> 6, lane = gid & 63;
    if (w >= n) return;
    int beg = rs[w], end = rs[w + 1];
    float ax = 0.f, ay = 0.f;
    for (int i = beg; i < end; ++i) {
        int u = csr[i];                       // wave-uniform -> scalar load
        unsigned v = h0s[(size_t)u * 64 + lane];
        ax += __uint_as_float(v << 16);
        ay += __uint_as_float(v & 0xffff0000u);
    }
    float nv = norm[w];
    h1b[(size_t)w * 64 + lane] = pack2bf(ax * nv, ay * nv);
}

// ---------------- SpMM hop 2: gather h1b, norm[u] applied in-loop ----------------
// writes h2b = bf16(h2)
__global__ __launch_bounds__(TPB) void spmm2_kernel(
    const unsigned* __restrict__ h1b, const int* __restrict__ rs,
    const int* __restrict__ csr, const float* __restrict__ norm,
    unsigned* __restrict__ h2b, int n) {
    int gid = blockIdx.x * TPB + threadIdx.x;
    int w = gid >> 6, lane = gid & 63;
    if (w >= n) return;
    int beg = rs[w], end = rs[w + 1];
    float ax = 0.f, ay = 0.f;
    for (int i = beg; i < end; ++i) {
        int u = csr[i];                       // wave-uniform
        float s = norm[u];                    // wave-uniform broadcast
        unsigned v = h1b[(size_t)u * 64 + lane];
        ax = fmaf(s, __uint_as_float(v << 16), ax);
        ay = fmaf(s, __uint_as_float(v & 0xffff0000u), ay);
    }
    float nv = norm[w];
    h2b[(size_t)w * 64 + lane] = pack2bf(ax * nv, ay * nv);
}

// ---------------- GEMM: out[n][128] = [featb|h1b|h2b] @ Wb^T + b (bf16 MFMA) ----
// block = 256 thr = 4 waves, tile 32 rows x 128 cols (2 waves M x 2 waves N).
// A frag layout: m = lane&15, k = (lane>>4)*8 + j  [verified m89/m91]
// B frag layout: ncol = lane&15, k = (lane>>4)*8 + j
// C/D: col = lane&15, row = (lane>>4)*4 + reg
__global__ __launch_bounds__(TPB) void gemm_mfma_kernel(
    const ushort* __restrict__ featb, const ushort* __restrict__ h1b,
    const ushort* __restrict__ h2b, const ushort* __restrict__ Wb,
    const float* __restrict__ bias, float* __restrict__ out, int n) {
    int lane = threadIdx.x & 63;
    int wave = threadIdx.x >> 6;
    int mw = wave >> 1, nw = wave & 1;
    int m = lane & 15, q = lane >> 4;
    int node = blockIdx.x * 32 + mw * 16 + m;
    const ushort* srcs[3] = {featb, h1b, h2b};
    f32x4 acc[4] = {};
    bool vr = node < n;
    size_t nrow = (size_t)node * D;
#pragma unroll
    for (int ks = 0; ks < 12; ++ks) {
        short8 a = {};
        if (vr) a = *(const short8*)(srcs[ks >> 2] + nrow + (ks & 3) * 32 + q * 8);
#pragma unroll
        for (int t = 0; t < 4; ++t) {
            int ncol = nw * 64 + t * 16 + m;
            short8 b = *(const short8*)(Wb + (size_t)ncol * 384 + ks * 32 + q * 8);
            acc[t] = __builtin_amdgcn_mfma_f32_16x16x32_bf16(a, b, acc[t], 0, 0, 0);
        }
    }
    int orow0 = blockIdx.x * 32 + mw * 16 + q * 4;
#pragma unroll
    for (int t = 0; t < 4; ++t) {
        int ncol = nw * 64 + t * 16 + m;
        float bv = bias[ncol];
#pragma unroll
        for (int r = 0; r < 4; ++r) {
            int nr = orow0 + r;
            if (nr < n) out[(size_t)nr * D + ncol] = acc[t][r] + bv;
        }
    }
}

extern "C" void kernel_launch(void* const* d_in, const int* in_sizes, int n_in,
                              void* d_out, int out_size, void* d_ws, size_t ws_size,
                              hipStream_t stream) {
    const float* feat = (const float*)d_in[0];
    const int* src    = (const int*)d_in[1];
    const int* dst    = (const int*)d_in[2];
    const float* W    = (const float*)d_in[3];
    const float* bias = (const float*)d_in[4];
    float* out        = (float*)d_out;

    const int N = in_sizes[0] / D;     // 100000
    const int E = in_sizes[1];         // 1600000

    char* ws = (char*)d_ws;
    size_t off = 0;
    auto bump = [&](size_t bytes) {
        char* p = ws + off;
        off += (bytes + 255) & ~(size_t)255;
        return p;
    };
    int* deg        = (int*)bump((size_t)N * 4);       // zeroed below (adjacent w/ cursor)
    int* cursor     = (int*)bump((size_t)N * 4);       // zeroed below
    float* norm     = (float*)bump((size_t)N * 4);
    int* rs         = (int*)bump((size_t)(N + 1) * 4);
    int* bsum       = (int*)bump(512 * 4);
    int* csr        = (int*)bump((size_t)E * 4);
    unsigned* featb = (unsigned*)bump((size_t)N * 64 * 4);   // bf16x2 rows
    unsigned* h0s   = (unsigned*)bump((size_t)N * 64 * 4);
    unsigned* h1b   = (unsigned*)bump((size_t)N * 64 * 4);
    unsigned* h2b   = (unsigned*)bump((size_t)N * 64 * 4);
    ushort* Wb      = (ushort*)bump((size_t)D * 384 * 2);
    (void)ws_size;

    const int nb_n  = (N + TPB - 1) / TPB;
    const int nb_e  = (E + TPB - 1) / TPB;
    const int nb_n1 = (N + 1 + TPB - 1) / TPB;

    // zero deg + cursor (adjacent allocations)
    hipMemsetAsync(deg, 0, (((size_t)N * 4 + 255) & ~(size_t)255) + (size_t)N * 4, stream);

    deg_kernel<<<nb_e, TPB, 0, stream>>>(dst, deg, E);
    scan1_kernel<<<nb_n, TPB, 0, stream>>>(deg, rs, bsum, N);
    scan2_kernel<<<1, 512, 0, stream>>>(bsum, nb_n);
    finalize_kernel<<<nb_n1, TPB, 0, stream>>>(rs, bsum, deg, norm, N, E);
    scatter_kernel<<<nb_e, TPB, 0, stream>>>(src, dst, rs, cursor, csr, E);

    const int pres_blocks = (N * 64 + TPB - 1) / TPB;
    prescale_kernel<<<pres_blocks, TPB, 0, stream>>>(feat, norm, featb, h0s, N);
    wconv_kernel<<<(D * 384 + TPB - 1) / TPB, TPB, 0, stream>>>(W, Wb, D * 384);

    const int spmm_blocks = (N * 64 + TPB - 1) / TPB;  // 1 wave per node
    spmm1_kernel<<<spmm_blocks, TPB, 0, stream>>>(h0s, rs, csr, norm, h1b, N);
    spmm2_kernel<<<spmm_blocks, TPB, 0, stream>>>(h1b, rs, csr, norm, h2b, N);

    const int gemm_blocks = (N + 31) / 32;
    gemm_mfma_kernel<<<gemm_blocks, TPB, 0, stream>>>(
        (const ushort*)featb, (const ushort*)h1b, (const ushort*)h2b, Wb, bias, out, N);
}

// Round 3
// 464.015 us; speedup vs baseline: 1.5438x; 1.4092x over previous
//
#include <hip/hip_runtime.h>
#include <hip/hip_bf16.h>

// TAGConv K=2, D=128. Round 3: SpMM gathers 4 edges/iteration at 16 B/lane
// (1 KB per wave instruction) with quarter-wave edge parallelism + shfl_xor
// reduce. Single unified spmm kernel (norm[u] applied in-loop) for both hops.
// bf16 MFMA GEMM unchanged.

#define D 128
#define TPB 256

typedef __attribute__((ext_vector_type(8))) short short8;
typedef __attribute__((ext_vector_type(4))) float f32x4;

__device__ __forceinline__ ushort f2bf(float f) {
    unsigned u = __float_as_uint(f);
    u += 0x7fff + ((u >> 16) & 1);      // round-to-nearest-even
    return (ushort)(u >> 16);
}
__device__ __forceinline__ unsigned pack2bf(float x, float y) {
    return (unsigned)f2bf(x) | ((unsigned)f2bf(y) << 16);
}
__device__ __forceinline__ float bf_lo(unsigned v) { return __uint_as_float(v << 16); }
__device__ __forceinline__ float bf_hi(unsigned v) { return __uint_as_float(v & 0xffff0000u); }

// ---------------- degree ----------------
__global__ void deg_kernel(const int* __restrict__ dst, int* __restrict__ deg, int e) {
    int i = blockIdx.x * TPB + threadIdx.x;
    if (i < e) atomicAdd(&deg[dst[i]], 1);
}

// ---------------- exclusive scan over deg ----------------
__global__ void scan1_kernel(const int* __restrict__ deg, int* __restrict__ rs,
                             int* __restrict__ bsum, int n) {
    __shared__ int s[TPB];
    int t = threadIdx.x;
    int i = blockIdx.x * TPB + t;
    int v = (i < n) ? deg[i] : 0;
    s[t] = v;
    __syncthreads();
    for (int off = 1; off < TPB; off <<= 1) {
        int x = (t >= off) ? s[t - off] : 0;
        __syncthreads();
        s[t] += x;
        __syncthreads();
    }
    if (i < n) rs[i] = s[t] - v;
    if (t == TPB - 1) bsum[blockIdx.x] = s[t];
}

__global__ void scan2_kernel(int* __restrict__ bsum, int nb) {
    __shared__ int s[512];
    int t = threadIdx.x;
    int v = (t < nb) ? bsum[t] : 0;
    s[t] = v;
    __syncthreads();
    for (int off = 1; off < 512; off <<= 1) {
        int x = (t >= off) ? s[t - off] : 0;
        __syncthreads();
        s[t] += x;
        __syncthreads();
    }
    if (t < nb) bsum[t] = s[t] - v;
}

__global__ void finalize_kernel(int* __restrict__ rs, const int* __restrict__ bsum,
                                const int* __restrict__ deg, float* __restrict__ norm,
                                int n, int e_total) {
    int i = blockIdx.x * TPB + threadIdx.x;
    if (i < n) {
        rs[i] += bsum[blockIdx.x];
        norm[i] = rsqrtf((float)deg[i]);
    }
    if (i == n) rs[n] = e_total;
}

// ---------------- CSR scatter ----------------
__global__ void scatter_kernel(const int* __restrict__ src, const int* __restrict__ dst,
                               const int* __restrict__ rs, int* __restrict__ cursor,
                               int* __restrict__ csr, int e) {
    int i = blockIdx.x * TPB + threadIdx.x;
    if (i < e) {
        int v = dst[i];
        int pos = rs[v] + atomicAdd(&cursor[v], 1);
        csr[pos] = src[i];
    }
}

// ---------------- prescale: featb = bf16(feat) ----------------
__global__ __launch_bounds__(TPB) void prescale_kernel(
    const float* __restrict__ feat, unsigned* __restrict__ featb, int n) {
    int gid = blockIdx.x * TPB + threadIdx.x;
    int node = gid >> 6, c = gid & 63;
    if (node >= n) return;
    float2 f = ((const float2*)(feat + (size_t)node * D))[c];
    featb[(size_t)node * 64 + c] = pack2bf(f.x, f.y);
}

// ---------------- W -> bf16 ----------------
__global__ void wconv_kernel(const float* __restrict__ W, ushort* __restrict__ Wb, int n) {
    int i = blockIdx.x * TPB + threadIdx.x;
    if (i < n) Wb[i] = f2bf(W[i]);
}

// ---------------- SpMM: hout[v] = bf16( norm[v] * sum_u norm[u]*hin[u] ) ----
// One wave per dst node. Quarter-wave q = lane>>4 handles edge (beg+j*4+q);
// c = lane&15 handles 16B column chunk (cols c*8 .. c*8+7).
// Each gather instruction: 4 edges x 256 B = 1 KB.
__global__ __launch_bounds__(TPB) void spmm_kernel(
    const unsigned* __restrict__ hin, const int* __restrict__ rs,
    const int* __restrict__ csr, const float* __restrict__ norm,
    unsigned* __restrict__ hout, int n) {
    int w = (blockIdx.x * TPB + threadIdx.x) >> 6;
    if (w >= n) return;
    int lane = threadIdx.x & 63;
    int q = lane >> 4;
    int c = lane & 15;
    int beg = rs[w], end = rs[w + 1];
    float acc[8] = {};
#pragma unroll 2
    for (int j = beg + q; j < end; j += 4) {
        int u = csr[j];                    // broadcast within quarter-wave
        float s = norm[u];                 // L2-resident 400KB table
        uint4 v = *(const uint4*)(hin + (size_t)u * 64 + c * 4);
        acc[0] = fmaf(s, bf_lo(v.x), acc[0]);
        acc[1] = fmaf(s, bf_hi(v.x), acc[1]);
        acc[2] = fmaf(s, bf_lo(v.y), acc[2]);
        acc[3] = fmaf(s, bf_hi(v.y), acc[3]);
        acc[4] = fmaf(s, bf_lo(v.z), acc[4]);
        acc[5] = fmaf(s, bf_hi(v.z), acc[5]);
        acc[6] = fmaf(s, bf_lo(v.w), acc[6]);
        acc[7] = fmaf(s, bf_hi(v.w), acc[7]);
    }
    // reduce across the 4 quarter-waves (lanes differing in bits 4,5)
#pragma unroll
    for (int k = 0; k < 8; ++k) {
        acc[k] += __shfl_xor(acc[k], 16, 64);
        acc[k] += __shfl_xor(acc[k], 32, 64);
    }
    if (q == 0) {
        float nv = norm[w];
        uint4 r;
        r.x = pack2bf(acc[0] * nv, acc[1] * nv);
        r.y = pack2bf(acc[2] * nv, acc[3] * nv);
        r.z = pack2bf(acc[4] * nv, acc[5] * nv);
        r.w = pack2bf(acc[6] * nv, acc[7] * nv);
        *(uint4*)(hout + (size_t)w * 64 + c * 4) = r;   // 16 lanes x 16B = 256 B
    }
}

// ---------------- GEMM: out[n][128] = [featb|h1b|h2b] @ Wb^T + b (bf16 MFMA) ----
// block = 256 thr = 4 waves, tile 32 rows x 128 cols (2 waves M x 2 waves N).
// A frag: m = lane&15, k = (lane>>4)*8 + j.  C/D: col = lane&15, row = (lane>>4)*4 + reg.
__global__ __launch_bounds__(TPB) void gemm_mfma_kernel(
    const ushort* __restrict__ featb, const ushort* __restrict__ h1b,
    const ushort* __restrict__ h2b, const ushort* __restrict__ Wb,
    const float* __restrict__ bias, float* __restrict__ out, int n) {
    int lane = threadIdx.x & 63;
    int wave = threadIdx.x >> 6;
    int mw = wave >> 1, nw = wave & 1;
    int m = lane & 15, q = lane >> 4;
    int node = blockIdx.x * 32 + mw * 16 + m;
    const ushort* srcs[3] = {featb, h1b, h2b};
    f32x4 acc[4] = {};
    bool vr = node < n;
    size_t nrow = (size_t)node * D;
#pragma unroll
    for (int ks = 0; ks < 12; ++ks) {
        short8 a = {};
        if (vr) a = *(const short8*)(srcs[ks >> 2] + nrow + (ks & 3) * 32 + q * 8);
#pragma unroll
        for (int t = 0; t < 4; ++t) {
            int ncol = nw * 64 + t * 16 + m;
            short8 b = *(const short8*)(Wb + (size_t)ncol * 384 + ks * 32 + q * 8);
            acc[t] = __builtin_amdgcn_mfma_f32_16x16x32_bf16(a, b, acc[t], 0, 0, 0);
        }
    }
    int orow0 = blockIdx.x * 32 + mw * 16 + q * 4;
#pragma unroll
    for (int t = 0; t < 4; ++t) {
        int ncol = nw * 64 + t * 16 + m;
        float bv = bias[ncol];
#pragma unroll
        for (int r = 0; r < 4; ++r) {
            int nr = orow0 + r;
            if (nr < n) out[(size_t)nr * D + ncol] = acc[t][r] + bv;
        }
    }
}

extern "C" void kernel_launch(void* const* d_in, const int* in_sizes, int n_in,
                              void* d_out, int out_size, void* d_ws, size_t ws_size,
                              hipStream_t stream) {
    const float* feat = (const float*)d_in[0];
    const int* src    = (const int*)d_in[1];
    const int* dst    = (const int*)d_in[2];
    const float* W    = (const float*)d_in[3];
    const float* bias = (const float*)d_in[4];
    float* out        = (float*)d_out;

    const int N = in_sizes[0] / D;     // 100000
    const int E = in_sizes[1];         // 1600000

    char* ws = (char*)d_ws;
    size_t off = 0;
    auto bump = [&](size_t bytes) {
        char* p = ws + off;
        off += (bytes + 255) & ~(size_t)255;
        return p;
    };
    int* deg        = (int*)bump((size_t)N * 4);       // zeroed below (adjacent w/ cursor)
    int* cursor     = (int*)bump((size_t)N * 4);       // zeroed below
    float* norm     = (float*)bump((size_t)N * 4);
    int* rs         = (int*)bump((size_t)(N + 1) * 4);
    int* bsum       = (int*)bump(512 * 4);
    int* csr        = (int*)bump((size_t)E * 4);
    unsigned* featb = (unsigned*)bump((size_t)N * 64 * 4);   // bf16x2 rows
    unsigned* h1b   = (unsigned*)bump((size_t)N * 64 * 4);
    unsigned* h2b   = (unsigned*)bump((size_t)N * 64 * 4);
    ushort* Wb      = (ushort*)bump((size_t)D * 384 * 2);
    (void)ws_size;

    const int nb_n  = (N + TPB - 1) / TPB;
    const int nb_e  = (E + TPB - 1) / TPB;
    const int nb_n1 = (N + 1 + TPB - 1) / TPB;

    // zero deg + cursor (adjacent allocations)
    hipMemsetAsync(deg, 0, (((size_t)N * 4 + 255) & ~(size_t)255) + (size_t)N * 4, stream);

    deg_kernel<<<nb_e, TPB, 0, stream>>>(dst, deg, E);
    scan1_kernel<<<nb_n, TPB, 0, stream>>>(deg, rs, bsum, N);
    scan2_kernel<<<1, 512, 0, stream>>>(bsum, nb_n);
    finalize_kernel<<<nb_n1, TPB, 0, stream>>>(rs, bsum, deg, norm, N, E);
    scatter_kernel<<<nb_e, TPB, 0, stream>>>(src, dst, rs, cursor, csr, E);

    const int pres_blocks = (N * 64 + TPB - 1) / TPB;
    prescale_kernel<<<pres_blocks, TPB, 0, stream>>>(feat, featb, N);
    wconv_kernel<<<(D * 384 + TPB - 1) / TPB, TPB, 0, stream>>>(W, Wb, D * 384);

    const int spmm_blocks = (N * 64 + TPB - 1) / TPB;  // 1 wave per node
    spmm_kernel<<<spmm_blocks, TPB, 0, stream>>>(featb, rs, csr, norm, h1b, N);
    spmm_kernel<<<spmm_blocks, TPB, 0, stream>>>(h1b, rs, csr, norm, h2b, N);

    const int gemm_blocks = (N + 31) / 32;
    gemm_mfma_kernel<<<gemm_blocks, TPB, 0, stream>>>(
        (const ushort*)featb, (const ushort*)h1b, (const ushort*)h2b, Wb, bias, out, N);
}